// Round 1
// baseline (103.402 us; speedup 1.0000x reference)
//
#include <hip/hip_runtime.h>

#define NBLOCKS 45
#define NBATCH  4
#define SEQ     2880
#define EMB     512
#define BLK     64

typedef __attribute__((ext_vector_type(8))) short short8;
typedef __attribute__((ext_vector_type(4))) float floatx4;

// LDS strides (in elements)
#define QSTR 264   // ushort, q tile rows: 528 B (16B aligned, 2-way banks)
#define XSTR 88    // ushort, x^T rows: 176 B (16B aligned, 2-way banks)
#define PSTR 72    // ushort, P rows: 144 B (16B aligned)
#define SSTR 65    // float, score rows

__device__ __forceinline__ unsigned short f2bf(float f) {
    unsigned int x = __float_as_uint(f);
    unsigned int r = (x + 0x7fffu + ((x >> 16) & 1u)) >> 16;  // RNE
    return (unsigned short)r;
}

// Wave-wide top-8 indices of v (desc, ties -> lowest index), returns bitmask.
// Matches jax.lax.top_k tie-breaking.
__device__ __forceinline__ unsigned long long topk8_mask(float v, int lane) {
    unsigned long long res = 0ull;
    bool alive = true;
    for (int k = 0; k < 8; ++k) {
        float bv = alive ? v : -__builtin_inff();
        int bi = lane;
        #pragma unroll
        for (int off = 1; off < 64; off <<= 1) {
            float ov = __shfl_xor(bv, off);
            int oi = __shfl_xor(bi, off);
            if (ov > bv || (ov == bv && oi < bi)) { bv = ov; bi = oi; }
        }
        res |= 1ull << bi;           // bi identical across lanes
        if (lane == bi) alive = false;
    }
    return res;
}

__global__ __launch_bounds__(512) void nsparse_attn(
    const float* __restrict__ x,
    const float* __restrict__ phi,
    const float* __restrict__ pos,
    float* __restrict__ out)
{
    __shared__ __align__(16) unsigned char s_buf[256 * XSTR * 2];  // 45056 B, phase-shared
    __shared__ __align__(16) unsigned short s_P[BLK * PSTR];       // 9216 B
    __shared__ int s_sel[BLK];

    const int tid  = threadIdx.x;
    const int wave = tid >> 6;
    const int lane = tid & 63;
    const int quad = lane >> 4;
    const int lcol = lane & 15;

    const int nb = blockIdx.x;
    const int b  = blockIdx.y;
    const int t0 = nb * BLK;

    const float* xb = x + ((size_t)b * SEQ + t0) * EMB;
    float* ob = out + ((size_t)b * SEQ + t0) * EMB;

    // ---- selection mask from phi[:64] (wave 0; replicates _block_sparse_mask) ----
    if (wave == 0) {
        float pv = phi[lane];
        unsigned long long bp = __ballot(pv > 0.0f);
        unsigned long long bn = __ballot(pv < 0.0f);
        unsigned long long bz = __ballot(pv == 0.0f);
        unsigned long long selm = 0ull;
        if (bz) selm |= 0xffull;                    // all-zero rows pick idx 0..7
        if (bp) selm |= topk8_mask(pv, lane);       // rows with p[i]>0 -> top-8 of p
        if (bn) selm |= topk8_mask(-pv, lane);      // rows with p[i]<0 -> bottom-8 of p
        s_sel[lane] = (int)((selm >> lane) & 1ull);
    }

    // ---- phase 1: S = q q^T / sqrt(E), q = x + pos + phi (bf16 MFMA, f32 acc) ----
    unsigned short* qb = (unsigned short*)s_buf;   // [BLK][QSTR]
    const int mi  = wave >> 1;          // row-tile 0..3
    const int ni0 = (wave & 1) * 2;     // col-tiles {0,1} or {2,3}

    floatx4 accS0 = {0.f, 0.f, 0.f, 0.f};
    floatx4 accS1 = {0.f, 0.f, 0.f, 0.f};

    for (int kc = 0; kc < 2; ++kc) {   // K chunks of 256
        if (kc) __syncthreads();
        const int e0 = kc * 256;
        // stage q chunk: row r = wave+8k (uniform/wave), lanes cover 64 float4 cols
        #pragma unroll
        for (int k = 0; k < 8; ++k) {
            const int r = wave + 8 * k;
            const float4 xv = *(const float4*)(xb  + (size_t)r * EMB + e0 + lane * 4);
            const float4 pv = *(const float4*)(pos + (size_t)(t0 + r) * EMB + e0 + lane * 4);
            const float4 fv = *(const float4*)(phi + e0 + lane * 4);
            unsigned short u0 = f2bf(xv.x + pv.x + fv.x);
            unsigned short u1 = f2bf(xv.y + pv.y + fv.y);
            unsigned short u2 = f2bf(xv.z + pv.z + fv.z);
            unsigned short u3 = f2bf(xv.w + pv.w + fv.w);
            unsigned int w0 = (unsigned int)u0 | ((unsigned int)u1 << 16);
            unsigned int w1 = (unsigned int)u2 | ((unsigned int)u3 << 16);
            *(uint2*)&qb[r * QSTR + lane * 4] = make_uint2(w0, w1);
        }
        __syncthreads();
        #pragma unroll
        for (int ks = 0; ks < 8; ++ks) {           // K-steps of 32
            const int koff = ks * 32 + quad * 8;
            short8 a  = *(const short8*)&qb[(mi  * 16 + lcol) * QSTR + koff];
            short8 b0 = *(const short8*)&qb[(ni0 * 16 + lcol) * QSTR + koff];
            short8 b1 = *(const short8*)&qb[((ni0 + 1) * 16 + lcol) * QSTR + koff];
            accS0 = __builtin_amdgcn_mfma_f32_16x16x32_bf16(a, b0, accS0, 0, 0, 0);
            accS1 = __builtin_amdgcn_mfma_f32_16x16x32_bf16(a, b1, accS1, 0, 0, 0);
        }
    }
    __syncthreads();   // q reads done; reuse s_buf for scores

    // ---- dump scaled scores (C/D layout: col=lane&15, row=quad*4+reg) ----
    float* Sb = (float*)s_buf;   // [BLK][SSTR]
    const float scale = 0.044194173824159216f;     // 1/sqrt(512)
    #pragma unroll
    for (int r = 0; r < 4; ++r) {
        const int row = mi * 16 + quad * 4 + r;
        Sb[row * SSTR + (ni0       * 16 + lcol)] = accS0[r] * scale;
        Sb[row * SSTR + ((ni0 + 1) * 16 + lcol)] = accS1[r] * scale;
    }
    __syncthreads();

    // ---- softmax over the 64 in-block keys; P -> bf16 A-layout ----
    {
        const int srow = tid >> 3;     // 8 threads per row
        const int sj = tid & 7;
        float v[8];
        float m = -__builtin_inff();
        #pragma unroll
        for (int i = 0; i < 8; ++i) {
            v[i] = Sb[srow * SSTR + sj + 8 * i];
            m = fmaxf(m, v[i]);
        }
        #pragma unroll
        for (int off = 1; off < 8; off <<= 1) m = fmaxf(m, __shfl_xor(m, off));
        float s = 0.f;
        #pragma unroll
        for (int i = 0; i < 8; ++i) { v[i] = __expf(v[i] - m); s += v[i]; }
        #pragma unroll
        for (int off = 1; off < 8; off <<= 1) s += __shfl_xor(s, off);
        const float inv = 1.0f / s;
        #pragma unroll
        for (int i = 0; i < 8; ++i) s_P[srow * PSTR + sj + 8 * i] = f2bf(v[i] * inv);
    }
    __syncthreads();   // Sb reads done; reuse s_buf for x^T

    // ---- phase 3: out = P @ x (contraction over t needs x^T in LDS) ----
    unsigned short* xT = (unsigned short*)s_buf;   // [256 e][XSTR], col = t
    for (int ec = 0; ec < 2; ++ec) {               // e chunks of 256
        if (ec) __syncthreads();
        const int e0 = ec * 256;
        // stage transpose: lane = t row (scattered 16B global reads, L2-hot from phase 1),
        // writes are lane-consecutive -> conflict-free
        #pragma unroll
        for (int k = 0; k < 8; ++k) {
            const int c4 = wave + 8 * k;
            const float4 xv = *(const float4*)(xb + (size_t)lane * EMB + e0 + c4 * 4);
            xT[(c4 * 4 + 0) * XSTR + lane] = f2bf(xv.x);
            xT[(c4 * 4 + 1) * XSTR + lane] = f2bf(xv.y);
            xT[(c4 * 4 + 2) * XSTR + lane] = f2bf(xv.z);
            xT[(c4 * 4 + 3) * XSTR + lane] = f2bf(xv.w);
        }
        __syncthreads();
        // A-fragments (P rows for this wave's row-tile), reused across 8 n-tiles
        short8 a0 = *(const short8*)&s_P[(mi * 16 + lcol) * PSTR + 0 + quad * 8];
        short8 a1 = *(const short8*)&s_P[(mi * 16 + lcol) * PSTR + 32 + quad * 8];
        #pragma unroll
        for (int j = 0; j < 8; ++j) {
            const int nt = (wave & 1) + 2 * j;     // 16-wide e tile within chunk
            short8 bf0 = *(const short8*)&xT[(nt * 16 + lcol) * XSTR + 0 + quad * 8];
            short8 bf1 = *(const short8*)&xT[(nt * 16 + lcol) * XSTR + 32 + quad * 8];
            floatx4 acc = {0.f, 0.f, 0.f, 0.f};
            acc = __builtin_amdgcn_mfma_f32_16x16x32_bf16(a0, bf0, acc, 0, 0, 0);
            acc = __builtin_amdgcn_mfma_f32_16x16x32_bf16(a1, bf1, acc, 0, 0, 0);
            #pragma unroll
            for (int r = 0; r < 4; ++r) {
                const int row = mi * 16 + quad * 4 + r;
                const int col = e0 + nt * 16 + lcol;
                ob[(size_t)row * EMB + col] = s_sel[row] ? acc[r] : 0.0f;
            }
        }
    }
}

extern "C" void kernel_launch(void* const* d_in, const int* in_sizes, int n_in,
                              void* d_out, int out_size, void* d_ws, size_t ws_size,
                              hipStream_t stream) {
    const float* x   = (const float*)d_in[0];
    const float* phi = (const float*)d_in[1];
    const float* pos = (const float*)d_in[2];
    float* out = (float*)d_out;
    dim3 grid(NBLOCKS, NBATCH);
    hipLaunchKernelGGL(nsparse_attn, grid, dim3(512), 0, stream, x, phi, pos, out);
}

// Round 2
// 96.054 us; speedup vs baseline: 1.0765x; 1.0765x over previous
//
#include <hip/hip_runtime.h>
#include <hip/hip_bf16.h>

#define NBLOCKS 45
#define NBATCH  4
#define SEQ     2880
#define EMB     512
#define BLK     64

typedef __attribute__((ext_vector_type(8))) short short8;
typedef __attribute__((ext_vector_type(4))) float floatx4;

// LDS strides (in elements)
#define QSTR 264   // ushort, q chunk rows: 256 e + 8 pad -> 528 B (16B aligned, 2-way banks = free)
#define XSTR 72    // ushort, xT rows: 64 t + 8 pad -> 144 B (16B aligned)
#define PSTR 72    // ushort, compact P rows
#define SSTR 66    // float, compact score rows

__device__ __forceinline__ unsigned short f2bf(float f) {
    unsigned int x = __float_as_uint(f);
    unsigned int r = (x + 0x7fffu + ((x >> 16) & 1u)) >> 16;  // RNE
    return (unsigned short)r;
}

__device__ __forceinline__ unsigned int pk2bf(float a, float b) {
    __hip_bfloat162 h = __float22bfloat162_rn(make_float2(a, b));  // v_cvt_pk_bf16_f32
    union { __hip_bfloat162 h; unsigned int u; } cv; cv.h = h;
    return cv.u;
}

// Wave-wide top-8 indices of v (desc, ties -> lowest index), returns bitmask.
// Matches jax.lax.top_k tie-breaking. (Unchanged from round 1: absmax was 0.0.)
__device__ __forceinline__ unsigned long long topk8_mask(float v, int lane) {
    unsigned long long res = 0ull;
    bool alive = true;
    for (int k = 0; k < 8; ++k) {
        float bv = alive ? v : -__builtin_inff();
        int bi = lane;
        #pragma unroll
        for (int off = 1; off < 64; off <<= 1) {
            float ov = __shfl_xor(bv, off);
            int oi = __shfl_xor(bi, off);
            if (ov > bv || (ov == bv && oi < bi)) { bv = ov; bi = oi; }
        }
        res |= 1ull << bi;
        if (lane == bi) alive = false;
    }
    return res;
}

__global__ __launch_bounds__(512) void nsparse_attn(
    const float* __restrict__ x,
    const float* __restrict__ phi,
    const float* __restrict__ pos,
    float* __restrict__ out)
{
    __shared__ __align__(16) unsigned char s_buf[256 * XSTR * 2];   // 36864 B: q chunk (33792) / xT chunk (36864)
    __shared__ __align__(16) float s_S[32 * SSTR];                  // 8448 B compact scores
    __shared__ __align__(16) unsigned short s_Pc[32 * PSTR];        // 4608 B compact P (bf16)
    __shared__ int s_sel[BLK];
    __shared__ int s_glist[32];
    __shared__ int s_m;

    const int tid  = threadIdx.x;
    const int wave = tid >> 6;
    const int lane = tid & 63;
    const int quad = lane >> 4;
    const int lcol = lane & 15;

    const int nb = blockIdx.x;
    const int b  = blockIdx.y;
    const int t0 = nb * BLK;

    const float* xb = x + ((size_t)b * SEQ + t0) * EMB;
    float* ob = out + ((size_t)b * SEQ + t0) * EMB;

    // ---- selection mask + compacted row list from phi[:64] ----
    if (wave == 0) {
        float pv = phi[lane];
        unsigned long long bp = __ballot(pv > 0.0f);
        unsigned long long bn = __ballot(pv < 0.0f);
        unsigned long long bz = __ballot(pv == 0.0f);
        unsigned long long selm = 0ull;
        if (bz) selm |= 0xffull;
        if (bp) selm |= topk8_mask(pv, lane);
        if (bn) selm |= topk8_mask(-pv, lane);
        s_sel[lane] = (int)((selm >> lane) & 1ull);
        if (lane < 32) s_glist[lane] = 0;            // pad slots -> row 0 (never stored)
        if (lane == 0) s_m = __popcll(selm);
        if ((selm >> lane) & 1ull) {
            int rank = __popcll(selm & ((1ull << lane) - 1ull));
            s_glist[rank] = lane;
        }
    }

    unsigned short* qb = (unsigned short*)s_buf;     // [64][QSTR]

    // ---- stage q chunk 0 (e 0..255): q = x + pos + phi, bf16 ----
    {
        #pragma unroll
        for (int k = 0; k < 8; ++k) {
            const int r = wave + 8 * k;
            const float4 xv = *(const float4*)(xb  + (size_t)r * EMB + lane * 4);
            const float4 pv = *(const float4*)(pos + (size_t)(t0 + r) * EMB + lane * 4);
            const float4 fv = *(const float4*)(phi + lane * 4);
            uint2 w2;
            w2.x = pk2bf(xv.x + pv.x + fv.x, xv.y + pv.y + fv.y);
            w2.y = pk2bf(xv.z + pv.z + fv.z, xv.w + pv.w + fv.w);
            *(uint2*)&qb[r * QSTR + lane * 4] = w2;
        }
    }
    __syncthreads();                                 // B1: sel/glist + q chunk0 ready

    const int m  = s_m;
    const int NT = (m + 15) >> 4;                    // compact row-tiles (1, or 2 if m>16)
    const int mi = wave >> 2;                        // phase-1 row-tile of this wave
    const int ni = wave & 3;                         // phase-1 col-tile
    const bool a_on = (mi < NT);
    int a_row = 0;
    if (a_on) a_row = s_glist[mi * 16 + lcol];       // gathered A row for this lane

    floatx4 accS = {0.f, 0.f, 0.f, 0.f};
    if (a_on) {
        #pragma unroll
        for (int ks = 0; ks < 8; ++ks) {
            const int koff = ks * 32 + quad * 8;
            short8 a  = *(const short8*)&qb[a_row * QSTR + koff];
            short8 bb = *(const short8*)&qb[(ni * 16 + lcol) * QSTR + koff];
            accS = __builtin_amdgcn_mfma_f32_16x16x32_bf16(a, bb, accS, 0, 0, 0);
        }
    }

    // ---- zero-fill unselected output rows (75% of output; overlap with MFMA latency) ----
    {
        const float4 z4 = {0.f, 0.f, 0.f, 0.f};
        #pragma unroll
        for (int it = 0; it < 16; ++it) {
            const int idx = tid + it * 512;
            const int r = idx >> 7, c4 = idx & 127;
            if (!s_sel[r]) *(float4*)(ob + (size_t)r * EMB + c4 * 4) = z4;
        }
    }
    __syncthreads();                                 // B2: q chunk0 reads done

    // ---- stage q chunk 1 (e 256..511) ----
    {
        #pragma unroll
        for (int k = 0; k < 8; ++k) {
            const int r = wave + 8 * k;
            const float4 xv = *(const float4*)(xb  + (size_t)r * EMB + 256 + lane * 4);
            const float4 pv = *(const float4*)(pos + (size_t)(t0 + r) * EMB + 256 + lane * 4);
            const float4 fv = *(const float4*)(phi + 256 + lane * 4);
            uint2 w2;
            w2.x = pk2bf(xv.x + pv.x + fv.x, xv.y + pv.y + fv.y);
            w2.y = pk2bf(xv.z + pv.z + fv.z, xv.w + pv.w + fv.w);
            *(uint2*)&qb[r * QSTR + lane * 4] = w2;
        }
    }
    __syncthreads();                                 // B3: q chunk1 ready

    if (a_on) {
        #pragma unroll
        for (int ks = 0; ks < 8; ++ks) {
            const int koff = ks * 32 + quad * 8;
            short8 a  = *(const short8*)&qb[a_row * QSTR + koff];
            short8 bb = *(const short8*)&qb[(ni * 16 + lcol) * QSTR + koff];
            accS = __builtin_amdgcn_mfma_f32_16x16x32_bf16(a, bb, accS, 0, 0, 0);
        }
        // dump scaled compact scores (C/D: col=lane&15, row=quad*4+reg)
        const float scale = 0.044194173824159216f;   // 1/sqrt(512)
        #pragma unroll
        for (int r = 0; r < 4; ++r) {
            const int g = mi * 16 + quad * 4 + r;
            s_S[g * SSTR + ni * 16 + lcol] = accS[r] * scale;
        }
    }
    __syncthreads();                                 // B4: scores ready, q reads done

    unsigned short* xT = (unsigned short*)s_buf;     // [256 e][XSTR], col = t

    // ---- softmax on compact rows (waves 0..NT*2-1) | xT chunk0 staging (waves 4-7) ----
    if (tid < NT * 128) {
        const int g = tid >> 3;
        const int sj = tid & 7;
        float v[8];
        float mx = -__builtin_inff();
        #pragma unroll
        for (int i = 0; i < 8; ++i) {
            v[i] = s_S[g * SSTR + sj + 8 * i];
            mx = fmaxf(mx, v[i]);
        }
        #pragma unroll
        for (int off = 1; off < 8; off <<= 1) mx = fmaxf(mx, __shfl_xor(mx, off));
        float s = 0.f;
        #pragma unroll
        for (int i = 0; i < 8; ++i) { v[i] = __expf(v[i] - mx); s += v[i]; }
        #pragma unroll
        for (int off = 1; off < 8; off <<= 1) s += __shfl_xor(s, off);
        const float inv = 1.0f / s;
        #pragma unroll
        for (int i = 0; i < 8; ++i) s_Pc[g * PSTR + sj + 8 * i] = f2bf(v[i] * inv);
    } else if (wave >= 4) {
        #pragma unroll
        for (int k = 0; k < 16; ++k) {
            const int c4 = (wave - 4) + 4 * k;
            const float4 xv = *(const float4*)(xb + (size_t)lane * EMB + c4 * 4);
            xT[(c4 * 4 + 0) * XSTR + lane] = f2bf(xv.x);
            xT[(c4 * 4 + 1) * XSTR + lane] = f2bf(xv.y);
            xT[(c4 * 4 + 2) * XSTR + lane] = f2bf(xv.z);
            xT[(c4 * 4 + 3) * XSTR + lane] = f2bf(xv.w);
        }
    }
    __syncthreads();                                 // B5: P + xT chunk0 ready

    // ---- phase 3 chunk 0: out[sel rows, e 0..255] = P @ x ----
    #pragma unroll 1
    for (int mi3 = 0; mi3 < NT; ++mi3) {
        const short8 a0 = *(const short8*)&s_Pc[(mi3 * 16 + lcol) * PSTR + 0  + quad * 8];
        const short8 a1 = *(const short8*)&s_Pc[(mi3 * 16 + lcol) * PSTR + 32 + quad * 8];
        int rows[4]; bool val[4];
        #pragma unroll
        for (int r = 0; r < 4; ++r) {
            const int g = mi3 * 16 + quad * 4 + r;
            rows[r] = s_glist[g];
            val[r] = (g < m);
        }
        #pragma unroll
        for (int jj = 0; jj < 2; ++jj) {
            const int nt = wave + 8 * jj;
            const short8 b0 = *(const short8*)&xT[(nt * 16 + lcol) * XSTR + 0  + quad * 8];
            const short8 b1 = *(const short8*)&xT[(nt * 16 + lcol) * XSTR + 32 + quad * 8];
            floatx4 acc = {0.f, 0.f, 0.f, 0.f};
            acc = __builtin_amdgcn_mfma_f32_16x16x32_bf16(a0, b0, acc, 0, 0, 0);
            acc = __builtin_amdgcn_mfma_f32_16x16x32_bf16(a1, b1, acc, 0, 0, 0);
            #pragma unroll
            for (int r = 0; r < 4; ++r) {
                if (val[r]) ob[(size_t)rows[r] * EMB + nt * 16 + lcol] = acc[r];
            }
        }
    }
    __syncthreads();                                 // B6: xT chunk0 reads done

    // ---- stage xT chunk 1 (e 256..511), all waves ----
    {
        #pragma unroll
        for (int k = 0; k < 8; ++k) {
            const int c4 = wave + 8 * k;
            const float4 xv = *(const float4*)(xb + (size_t)lane * EMB + 256 + c4 * 4);
            xT[(c4 * 4 + 0) * XSTR + lane] = f2bf(xv.x);
            xT[(c4 * 4 + 1) * XSTR + lane] = f2bf(xv.y);
            xT[(c4 * 4 + 2) * XSTR + lane] = f2bf(xv.z);
            xT[(c4 * 4 + 3) * XSTR + lane] = f2bf(xv.w);
        }
    }
    __syncthreads();                                 // B7: xT chunk1 ready

    // ---- phase 3 chunk 1: out[sel rows, e 256..511] ----
    #pragma unroll 1
    for (int mi3 = 0; mi3 < NT; ++mi3) {
        const short8 a0 = *(const short8*)&s_Pc[(mi3 * 16 + lcol) * PSTR + 0  + quad * 8];
        const short8 a1 = *(const short8*)&s_Pc[(mi3 * 16 + lcol) * PSTR + 32 + quad * 8];
        int rows[4]; bool val[4];
        #pragma unroll
        for (int r = 0; r < 4; ++r) {
            const int g = mi3 * 16 + quad * 4 + r;
            rows[r] = s_glist[g];
            val[r] = (g < m);
        }
        #pragma unroll
        for (int jj = 0; jj < 2; ++jj) {
            const int nt = wave + 8 * jj;
            const short8 b0 = *(const short8*)&xT[(nt * 16 + lcol) * XSTR + 0  + quad * 8];
            const short8 b1 = *(const short8*)&xT[(nt * 16 + lcol) * XSTR + 32 + quad * 8];
            floatx4 acc = {0.f, 0.f, 0.f, 0.f};
            acc = __builtin_amdgcn_mfma_f32_16x16x32_bf16(a0, b0, acc, 0, 0, 0);
            acc = __builtin_amdgcn_mfma_f32_16x16x32_bf16(a1, b1, acc, 0, 0, 0);
            #pragma unroll
            for (int r = 0; r < 4; ++r) {
                if (val[r]) ob[(size_t)rows[r] * EMB + 256 + nt * 16 + lcol] = acc[r];
            }
        }
    }
}

extern "C" void kernel_launch(void* const* d_in, const int* in_sizes, int n_in,
                              void* d_out, int out_size, void* d_ws, size_t ws_size,
                              hipStream_t stream) {
    const float* x   = (const float*)d_in[0];
    const float* phi = (const float*)d_in[1];
    const float* pos = (const float*)d_in[2];
    float* out = (float*)d_out;
    dim3 grid(NBLOCKS, NBATCH);
    hipLaunchKernelGGL(nsparse_attn, grid, dim3(512), 0, stream, x, phi, pos, out);
}